// Round 2
// baseline (659.842 us; speedup 1.0000x reference)
//
#include <hip/hip_runtime.h>
#include <cmath>

typedef __bf16  v8bf  __attribute__((ext_vector_type(8)));
typedef __bf16  v2bf  __attribute__((ext_vector_type(2)));
typedef float   v4f   __attribute__((ext_vector_type(4)));

#define HH 56
#define WW2 56
#define WS 7
#define SS 3
#define HEADS 6
#define DIM 192
#define HID 768
#define BATCH 32
#define NTOK 49
#define NWIN 2048            // BATCH * 64
#define MTOT (NWIN * NTOK)   // 100352
#define SCALE 0.17677669529663687f

// region id in shifted-image coords: [0,49)=0, [49,53)=1, [53,56)=2
__device__ __forceinline__ int regid(int i) { return (i < 49) ? 0 : ((i < 53) ? 1 : 2); }

// ---------------------------------------------------------------------------
// Weight transpose + f32->bf16 cast: out[n*K + k] = (bf16)in[k*N + n]
// ---------------------------------------------------------------------------
__global__ void k_transpose(const float* __restrict__ in, __bf16* __restrict__ out,
                            int K, int N) {
    int idx = blockIdx.x * 256 + threadIdx.x;
    if (idx >= K * N) return;
    int n = idx / K, k = idx - n * K;
    out[idx] = (__bf16)in[k * N + n];
}

// ---------------------------------------------------------------------------
// LN1 + cyclic shift(-3,-3) + window partition. x f32 -> xw bf16 [w*49+p][c].
// One wave per token.
// ---------------------------------------------------------------------------
__global__ __launch_bounds__(256) void k_ln1win(const float* __restrict__ x,
                                                const float* __restrict__ g,
                                                const float* __restrict__ bt,
                                                __bf16* __restrict__ xw) {
    int wv = threadIdx.x >> 6, lane = threadIdx.x & 63;
    int t = blockIdx.x * 4 + wv;               // windowed token index
    int w = t / NTOK, p = t - w * NTOK;
    int b = w >> 6, wi = w & 63;
    int i = (wi >> 3) * 7 + p / 7;
    int j = (wi & 7) * 7 + p % 7;
    int io = i + SS; if (io >= HH) io -= HH;
    int jo = j + SS; if (jo >= WW2) jo -= WW2;
    const float* src = x + ((size_t)(b * 3136 + io * 56 + jo)) * DIM;
    float v0 = src[lane], v1 = src[lane + 64], v2 = src[lane + 128];
    float s = v0 + v1 + v2, s2 = v0 * v0 + v1 * v1 + v2 * v2;
    #pragma unroll
    for (int off = 1; off < 64; off <<= 1) {
        s  += __shfl_xor(s, off);
        s2 += __shfl_xor(s2, off);
    }
    float mu = s * (1.f / 192.f);
    float rstd = rsqrtf(s2 * (1.f / 192.f) - mu * mu + 1e-5f);
    __bf16* dst = xw + (size_t)t * DIM;
    dst[lane]       = (__bf16)((v0 - mu) * rstd * g[lane]       + bt[lane]);
    dst[lane + 64]  = (__bf16)((v1 - mu) * rstd * g[lane + 64]  + bt[lane + 64]);
    dst[lane + 128] = (__bf16)((v2 - mu) * rstd * g[lane + 128] + bt[lane + 128]);
}

// ---------------------------------------------------------------------------
// Tiled MFMA GEMM: C[M x N] = A[M x K] * Wt[N x K]^T + bias, with epilogues.
// MODE 0: qkv scatter (q scaled).  MODE 1: proj + window-reverse + residual -> x1 f32
// block 256 = 4 waves as 2x2, tile 64x64, k-step 32.
// ---------------------------------------------------------------------------
template<int KDIM, int MODE>
__global__ __launch_bounds__(256) void k_gemm(const __bf16* __restrict__ A,
                                              const __bf16* __restrict__ Wt,
                                              const float* __restrict__ bias,
                                              __bf16* __restrict__ qb,
                                              __bf16* __restrict__ kb,
                                              __bf16* __restrict__ vb,
                                              const float* __restrict__ xres,
                                              float* __restrict__ x1) {
    __shared__ __bf16 lA[64 * 40];
    __shared__ __bf16 lB[64 * 40];
    int tid = threadIdx.x;
    int m0 = blockIdx.x * 64;
    int n0 = blockIdx.y * 64;
    int wv = tid >> 6, lane = tid & 63;
    int wm = (wv >> 1) * 32, wn = (wv & 1) * 32;
    int lrow = lane & 15, lq = lane >> 4;
    int arow = tid >> 2, akc = (tid & 3) * 8;
    v4f acc[2][2] = {};
    for (int kk = 0; kk < KDIM; kk += 32) {
        *(v8bf*)(lA + arow * 40 + akc) = *(const v8bf*)(A  + (size_t)(m0 + arow) * KDIM + kk + akc);
        *(v8bf*)(lB + arow * 40 + akc) = *(const v8bf*)(Wt + (size_t)(n0 + arow) * KDIM + kk + akc);
        __syncthreads();
        #pragma unroll
        for (int a = 0; a < 2; a++) {
            v8bf af = *(const v8bf*)(lA + (wm + a * 16 + lrow) * 40 + lq * 8);
            #pragma unroll
            for (int b = 0; b < 2; b++) {
                v8bf bf = *(const v8bf*)(lB + (wn + b * 16 + lrow) * 40 + lq * 8);
                acc[a][b] = __builtin_amdgcn_mfma_f32_16x16x32_bf16(af, bf, acc[a][b], 0, 0, 0);
            }
        }
        __syncthreads();
    }
    #pragma unroll
    for (int a = 0; a < 2; a++)
    #pragma unroll
    for (int b = 0; b < 2; b++)
    #pragma unroll
    for (int r = 0; r < 4; r++) {
        int row = m0 + wm + a * 16 + lq * 4 + r;
        int col = n0 + wn + b * 16 + lrow;
        float v = acc[a][b][r] + bias[col];
        if (MODE == 0) {
            int which = col / DIM, rem = col - which * DIM;
            int h = rem >> 5, d = rem & 31;
            int w = row / NTOK, p = row - w * NTOK;
            size_t off = ((size_t)(w * HEADS + h) * NTOK + p) * 32 + d;
            if (which == 0)      qb[off] = (__bf16)(v * SCALE);
            else if (which == 1) kb[off] = (__bf16)v;
            else                 vb[off] = (__bf16)v;
        } else {
            int w = row / NTOK, p = row - w * NTOK;
            int bimg = w >> 6, wi = w & 63;
            int i = (wi >> 3) * 7 + p / 7;
            int j = (wi & 7) * 7 + p % 7;
            int io = i + SS; if (io >= HH) io -= HH;
            int jo = j + SS; if (jo >= WW2) jo -= WW2;
            size_t o = ((size_t)bimg * 3136 + io * 56 + jo) * DIM + col;
            x1[o] = v + xres[o];
        }
    }
}

// ---------------------------------------------------------------------------
// Windowed attention: one wave per (window, head).
// ---------------------------------------------------------------------------
__global__ __launch_bounds__(64) void k_attn(const __bf16* __restrict__ q,
                                             const __bf16* __restrict__ k,
                                             const __bf16* __restrict__ v,
                                             const float* __restrict__ rpb,
                                             __bf16* __restrict__ ao) {
    __shared__ float Kf[NTOK * 32];
    __shared__ float Vf[NTOK * 32];
    __shared__ float Sm[NTOK * NTOK];
    __shared__ float rl[169];
    int w = blockIdx.x, h = blockIdx.y;
    int tid = threadIdx.x;
    const __bf16* kbp = k + (size_t)(w * HEADS + h) * (NTOK * 32);
    const __bf16* vbp = v + (size_t)(w * HEADS + h) * (NTOK * 32);
    for (int idx = tid; idx < NTOK * 16; idx += 64) {
        v2bf kv = *(const v2bf*)(kbp + idx * 2);
        v2bf vv = *(const v2bf*)(vbp + idx * 2);
        *(float2*)(Kf + idx * 2) = make_float2((float)kv[0], (float)kv[1]);
        *(float2*)(Vf + idx * 2) = make_float2((float)vv[0], (float)vv[1]);
    }
    for (int idx = tid; idx < 169; idx += 64) rl[idx] = rpb[idx * 6 + h];
    __syncthreads();
    if (tid < NTOK) {
        int wi = w & 63;
        int i0 = (wi >> 3) * 7, j0 = (wi & 7) * 7;
        int ni = tid / 7, nj = tid - ni * 7;
        int cn = regid(i0 + ni) * 3 + regid(j0 + nj);
        float4 qr4[8];
        float* Qf = (float*)qr4;
        const __bf16* qp = q + ((size_t)(w * HEADS + h) * NTOK + tid) * 32;
        #pragma unroll
        for (int g = 0; g < 4; g++) {
            v8bf qv = *(const v8bf*)(qp + g * 8);
            #pragma unroll
            for (int jj = 0; jj < 8; jj++) Qf[g * 8 + jj] = (float)qv[jj];
        }
        float* Srow = Sm + tid * NTOK;
        float mx = -1e30f;
        for (int mi = 0; mi < 7; mi++) {
            int crm = regid(i0 + mi) * 3;
            for (int mj = 0; mj < 7; mj++) {
                int m = mi * 7 + mj;
                const float4* kp = (const float4*)(Kf + m * 32);
                float accv = 0.f;
                #pragma unroll
                for (int c = 0; c < 8; c++) {
                    float4 kv = kp[c];
                    float4 qv = qr4[c];
                    accv += qv.x * kv.x + qv.y * kv.y + qv.z * kv.z + qv.w * kv.w;
                }
                accv += rl[(ni - mi + 6) * 13 + (nj - mj + 6)];
                int cm = crm + regid(j0 + mj);
                accv += (cm == cn) ? 0.f : -100.f;
                mx = fmaxf(mx, accv);
                Srow[m] = accv;
            }
        }
        float den = 0.f;
        for (int m = 0; m < NTOK; m++) {
            float pp = __expf(Srow[m] - mx);
            den += pp;
            Srow[m] = pp;
        }
        float4 O4[8] = {};
        float* Of = (float*)O4;
        for (int m = 0; m < NTOK; m++) {
            float pp = Srow[m];
            const float4* vp = (const float4*)(Vf + m * 32);
            #pragma unroll
            for (int c = 0; c < 8; c++) {
                float4 vvv = vp[c];
                O4[c].x += pp * vvv.x; O4[c].y += pp * vvv.y;
                O4[c].z += pp * vvv.z; O4[c].w += pp * vvv.w;
            }
        }
        float inv = 1.f / den;
        __bf16* aop = ao + ((size_t)(w * NTOK + tid)) * DIM + h * 32;
        #pragma unroll
        for (int g = 0; g < 4; g++) {
            v8bf o8;
            #pragma unroll
            for (int jj = 0; jj < 8; jj++) o8[jj] = (__bf16)(Of[g * 8 + jj] * inv);
            *(v8bf*)(aop + g * 8) = o8;
        }
    }
}

// ---------------------------------------------------------------------------
// Fused MLP: out = x1 + (gelu(ln2(x1) @ fc1 + b1)) @ fc2 + b2     (out f32)
// block 256 (4 waves 2x2), 64 tokens/block, hidden chunked 6x128 through LDS.
// ---------------------------------------------------------------------------
__global__ __launch_bounds__(256) void k_mlp(const float* __restrict__ x1,
                                             const float* __restrict__ n2g,
                                             const float* __restrict__ n2b,
                                             const __bf16* __restrict__ fc1T,
                                             const float* __restrict__ fc1b,
                                             const __bf16* __restrict__ fc2T,
                                             const float* __restrict__ fc2b,
                                             float* __restrict__ out) {
    __shared__ __align__(16) char sm[75776];
    __bf16* aT  = (__bf16*)sm;                 // [64][200] bf16   (LN2 out)
    float*  lnf = (float*)(sm + 25600);        // [64][196] f32    (transient)
    __bf16* lB  = (__bf16*)(sm + 25600);       // [192][40] bf16
    __bf16* lH  = (__bf16*)(sm + 40960);       // [64][136] bf16
    int tid = threadIdx.x;
    int m0 = blockIdx.x * 64;
    int wv = tid >> 6, lane = tid & 63;
    int lrow = lane & 15, lq = lane >> 4;
    int wm = (wv >> 1) * 32, wnb = wv & 1;
    #pragma unroll
    for (int c = 0; c < 12; c++) {
        int idx = tid + c * 256;
        int row = idx / 48, c4 = (idx - row * 48) * 4;
        *(float4*)(lnf + row * 196 + c4) = *(const float4*)(x1 + (size_t)(m0 + row) * DIM + c4);
    }
    __syncthreads();
    {
        int row = tid >> 2, part = tid & 3;
        const float* rp = lnf + row * 196;
        float s = 0.f, s2 = 0.f;
        for (int i = part * 48; i < part * 48 + 48; i++) { float vv = rp[i]; s += vv; s2 += vv * vv; }
        s += __shfl_xor(s, 1); s2 += __shfl_xor(s2, 1);
        s += __shfl_xor(s, 2); s2 += __shfl_xor(s2, 2);
        float mu = s * (1.f / 192.f);
        float rstd = rsqrtf(s2 * (1.f / 192.f) - mu * mu + 1e-5f);
        __bf16* ap = aT + row * 200;
        for (int i = part * 48; i < part * 48 + 48; i++)
            ap[i] = (__bf16)((rp[i] - mu) * rstd * n2g[i] + n2b[i]);
    }
    __syncthreads();
    v4f yacc[2][6] = {};
    for (int hc = 0; hc < 6; hc++) {
        v4f hacc[2][4] = {};
        for (int ks = 0; ks < 6; ks++) {
            #pragma unroll
            for (int c = 0; c < 2; c++) {
                int nrow = (tid >> 2) + c * 64;
                int kc = (tid & 3) * 8;
                *(v8bf*)(lB + nrow * 40 + kc) =
                    *(const v8bf*)(fc1T + (size_t)(hc * 128 + nrow) * DIM + ks * 32 + kc);
            }
            __syncthreads();
            #pragma unroll
            for (int a = 0; a < 2; a++) {
                v8bf af = *(const v8bf*)(aT + (wm + a * 16 + lrow) * 200 + ks * 32 + lq * 8);
                #pragma unroll
                for (int b = 0; b < 4; b++) {
                    v8bf bf = *(const v8bf*)(lB + (wnb * 64 + b * 16 + lrow) * 40 + lq * 8);
                    hacc[a][b] = __builtin_amdgcn_mfma_f32_16x16x32_bf16(af, bf, hacc[a][b], 0, 0, 0);
                }
            }
            __syncthreads();
        }
        #pragma unroll
        for (int a = 0; a < 2; a++)
        #pragma unroll
        for (int b = 0; b < 4; b++)
        #pragma unroll
        for (int r = 0; r < 4; r++) {
            int row = wm + a * 16 + lq * 4 + r;
            int col = wnb * 64 + b * 16 + lrow;
            float hv = hacc[a][b][r] + fc1b[hc * 128 + col];
            float ge = 0.5f * hv * (1.f + erff(hv * 0.70710678118654752f));
            lH[row * 136 + col] = (__bf16)ge;
        }
        __syncthreads();
        for (int k2 = 0; k2 < 4; k2++) {
            #pragma unroll
            for (int c = 0; c < 3; c++) {
                int nrow = (tid >> 2) + c * 64;
                int kc = (tid & 3) * 8;
                *(v8bf*)(lB + nrow * 40 + kc) =
                    *(const v8bf*)(fc2T + (size_t)nrow * HID + hc * 128 + k2 * 32 + kc);
            }
            __syncthreads();
            #pragma unroll
            for (int a = 0; a < 2; a++) {
                v8bf af = *(const v8bf*)(lH + (wm + a * 16 + lrow) * 136 + k2 * 32 + lq * 8);
                #pragma unroll
                for (int b = 0; b < 6; b++) {
                    v8bf bf = *(const v8bf*)(lB + (wnb * 96 + b * 16 + lrow) * 40 + lq * 8);
                    yacc[a][b] = __builtin_amdgcn_mfma_f32_16x16x32_bf16(af, bf, yacc[a][b], 0, 0, 0);
                }
            }
            __syncthreads();
        }
    }
    #pragma unroll
    for (int a = 0; a < 2; a++)
    #pragma unroll
    for (int b = 0; b < 6; b++)
    #pragma unroll
    for (int r = 0; r < 4; r++) {
        int grow = m0 + wm + a * 16 + lq * 4 + r;
        int col = wnb * 96 + b * 16 + lrow;
        float vv = yacc[a][b][r] + fc2b[col] + x1[(size_t)grow * DIM + col];
        out[(size_t)grow * DIM + col] = vv;
    }
}

// ---------------------------------------------------------------------------
extern "C" void kernel_launch(void* const* d_in, const int* in_sizes, int n_in,
                              void* d_out, int out_size, void* d_ws, size_t ws_size,
                              hipStream_t stream) {
    const float* x      = (const float*)d_in[0];
    const float* n1g    = (const float*)d_in[1];
    const float* n1b    = (const float*)d_in[2];
    const float* qkv_w  = (const float*)d_in[3];
    const float* qkv_b  = (const float*)d_in[4];
    const float* rpb    = (const float*)d_in[5];
    const float* proj_w = (const float*)d_in[6];
    const float* proj_b = (const float*)d_in[7];
    const float* n2g    = (const float*)d_in[8];
    const float* n2b    = (const float*)d_in[9];
    const float* fc1_w  = (const float*)d_in[10];
    const float* fc1_b  = (const float*)d_in[11];
    const float* fc2_w  = (const float*)d_in[12];
    const float* fc2_b  = (const float*)d_in[13];
    float* outp = (float*)d_out;

    char* ws = (char*)d_ws;
    const size_t SZ = (size_t)MTOT * DIM * 2;   // 38,535,168 bytes
    __bf16* xw   = (__bf16*)(ws);               // also attention output (reused)
    __bf16* qb   = (__bf16*)(ws + SZ);
    __bf16* kb   = (__bf16*)(ws + 2 * SZ);
    __bf16* vb   = (__bf16*)(ws + 3 * SZ);
    float*  x1   = (float*)(ws + SZ);           // overlays q+k after attention
    __bf16* qkvT = (__bf16*)(ws + 4 * SZ);
    __bf16* projT = qkvT + 576 * 192;
    __bf16* fc1T  = projT + 192 * 192;
    __bf16* fc2T  = fc1T + 768 * 192;

    k_transpose<<<(192 * 576 + 255) / 256, 256, 0, stream>>>(qkv_w, qkvT, 192, 576);
    k_transpose<<<(192 * 192 + 255) / 256, 256, 0, stream>>>(proj_w, projT, 192, 192);
    k_transpose<<<(192 * 768 + 255) / 256, 256, 0, stream>>>(fc1_w, fc1T, 192, 768);
    k_transpose<<<(768 * 192 + 255) / 256, 256, 0, stream>>>(fc2_w, fc2T, 768, 192);

    k_ln1win<<<MTOT / 4, 256, 0, stream>>>(x, n1g, n1b, xw);

    k_gemm<192, 0><<<dim3(MTOT / 64, 9), 256, 0, stream>>>(
        xw, qkvT, qkv_b, qb, kb, vb, nullptr, nullptr);

    k_attn<<<dim3(NWIN, HEADS), 64, 0, stream>>>(qb, kb, vb, rpb, xw);

    k_gemm<192, 1><<<dim3(MTOT / 64, 3), 256, 0, stream>>>(
        xw, projT, proj_b, nullptr, nullptr, nullptr, x, x1);

    k_mlp<<<MTOT / 64, 256, 0, stream>>>(x1, n2g, n2b, fc1T, fc1_b, fc2T, fc2_b, outp);
}